// Round 9
// baseline (282.528 us; speedup 1.0000x reference)
//
#include <hip/hip_runtime.h>
#include <hip/hip_fp16.h>
#include <hip/hip_cooperative_groups.h>

namespace cg = cooperative_groups;

namespace {

constexpr int S = 512;        // plane height/width
constexpr int C = 64;         // channels per plane
constexpr int TILE = 16;      // texel tile side
constexpr int TPP  = 32;      // tiles per plane side (512/16)
constexpr int NBINS = 3 * TPP * TPP;   // 3072 bins = (plane, ty, tx)
constexpr int CAP = 744;      // slots per bin (lambda=512, +10 sigma)
constexpr int OVF_CAP = 8192; // overflow list capacity

constexpr int GRID_BLOCKS = 768;       // cooperative grid: 3 blocks/CU x 256 CU
constexpr int BINS_PER_BLOCK = 4;      // 3072 / 768

constexpr int HH = 17;        // halo rows
constexpr int HW = 17;        // halo cols
constexpr int TSTRIDE = 68;   // halves per texel slot (136B; 8B-aligned)
constexpr int LDSH = HH * HW * TSTRIDE;  // 19652 halves = 39304 B

typedef float f32x4 __attribute__((ext_vector_type(4)));
struct alignas(8) H4 { __half2 a, b; };
typedef unsigned long long u64;

// q = floor((g+1)*262144)  ->  ix_q = q/1024 - 0.5, error <= 1/1024 texel,
// floor-consistent: x0 = (q-512)>>10 == floor(ix) for in-range inputs.
__device__ __forceinline__ unsigned quantg(float g)
{
    float v = (g + 1.0f) * 262144.0f;
    int q = (int)floorf(v);
    q = min(max(q, 0), 1048575);
    return (unsigned)q;
}

__device__ __forceinline__ int x0_of_q(unsigned q) { return ((int)q - 512) >> 10; }

__device__ __forceinline__ int bin_from_q(int p, unsigned qx, unsigned qy)
{
    int xc0 = min(max(x0_of_q(qx), 0), S - 1);
    int yc0 = min(max(x0_of_q(qy), 0), S - 1);
    return p * (TPP * TPP) + (yc0 >> 4) * TPP + (xc0 >> 4);
}

// ---------------------------------------------------------------------------
// Halo tile loader: 17x17 texels x 64 ch, channel-major f32 -> LDS f16,
// 136B texel stride.  512-thread block.  tasks = 64ch x 17rows x 5 x-segs.
// ---------------------------------------------------------------------------
__device__ __forceinline__ void halo_load(const float* __restrict__ tp, int bin,
                                          __half* __restrict__ tile)
{
    int p  = bin >> 10;
    int ty = (bin >> 5) & 31;
    int tx = bin & 31;
    int xg = tx * TILE;
    int yg = ty * TILE;
    const float* pl = tp + (size_t)p * C * (S * S);

    for (int task = threadIdx.x; task < C * HH * 5; task += 512) {
        int seg = task % 5;
        int rem = task / 5;
        int row = rem % HH;
        int ch  = rem / HH;
        int y   = min(yg + row, S - 1);
        int cb  = (seg < 4) ? seg * 4 : 13;
        int xb  = xg + cb;
        if (xb > S - 4) xb = S - 4;            // only tx=31, seg 4
        float4 v = *reinterpret_cast<const float4*>(pl + ((size_t)ch * S + y) * S + xb);
        __half* trow = &tile[(row * HW) * TSTRIDE + ch];
        #pragma unroll
        for (int i = 0; i < 4; ++i) {
            int col = xb + i - xg;
            if (col >= 0 && col < HW)
                trow[col * TSTRIDE] = __float2half(((const float*)&v)[i]);
        }
        if (xb != xg + cb)                      // tx=31: col 16 (weight-dead)
            trow[16 * TSTRIDE] = __float2half(((const float*)&v)[3]);
    }
}

// ---------------------------------------------------------------------------
// Phase-2 sampling of one bin from the LDS tile.  8 lanes/sample; H4 corner
// reads at c = 4t and 32+4t; two 128B-group-contiguous NT f32x4 stores.
// ---------------------------------------------------------------------------
__device__ __forceinline__ void sample_bin(int bin, int cnt,
                                           const u64* __restrict__ sb,
                                           const __half* __restrict__ tile,
                                           float* __restrict__ out)
{
    int xg = (bin & 31) * TILE;
    int yg = ((bin >> 5) & 31) * TILE;
    int grp = threadIdx.x >> 3;
    int t   = threadIdx.x & 7;

    for (int gi = grp; gi < cnt; gi += 64) {
        u64 rec = sb[gi];
        int sp = (int)(rec >> 40);
        unsigned qx = (unsigned)rec & 0xFFFFFu;
        unsigned qy = (unsigned)(rec >> 20) & 0xFFFFFu;

        float ix = (float)qx * (1.0f / 1024.0f) - 0.5f;
        float iy = (float)qy * (1.0f / 1024.0f) - 0.5f;
        int x0 = x0_of_q(qx), y0 = x0_of_q(qy);
        float wx = ix - (float)x0, wy = iy - (float)y0;
        int x1 = x0 + 1, y1 = y0 + 1;

        bool vx0 = ((unsigned)x0 < (unsigned)S);
        bool vx1 = ((unsigned)x1 < (unsigned)S);
        bool vy0 = ((unsigned)y0 < (unsigned)S);
        bool vy1 = ((unsigned)y1 < (unsigned)S);

        float w00 = (vx0 && vy0) ? (1.0f - wy) * (1.0f - wx) : 0.0f;
        float w01 = (vx1 && vy0) ? (1.0f - wy) * wx          : 0.0f;
        float w10 = (vx0 && vy1) ? wy * (1.0f - wx)          : 0.0f;
        float w11 = (vx1 && vy1) ? wy * wx                   : 0.0f;

        int lx0 = min(max(x0, 0), S - 1) - xg;
        int lx1 = min(max(x1, 0), S - 1) - xg;
        int ly0 = min(max(y0, 0), S - 1) - yg;
        int ly1 = min(max(y1, 0), S - 1) - yg;

        int o00 = (ly0 * HW + lx0) * TSTRIDE;
        int o01 = (ly0 * HW + lx1) * TSTRIDE;
        int o10 = (ly1 * HW + lx0) * TSTRIDE;
        int o11 = (ly1 * HW + lx1) * TSTRIDE;

        #pragma unroll
        for (int h = 0; h < 2; ++h) {
            int c = 4 * t + 32 * h;
            H4 v00 = *reinterpret_cast<const H4*>(&tile[o00 + c]);
            H4 v01 = *reinterpret_cast<const H4*>(&tile[o01 + c]);
            H4 v10 = *reinterpret_cast<const H4*>(&tile[o10 + c]);
            H4 v11 = *reinterpret_cast<const H4*>(&tile[o11 + c]);

            float2 a  = __half22float2(v00.a), a2 = __half22float2(v00.b);
            float2 bb = __half22float2(v01.a), b2 = __half22float2(v01.b);
            float2 cc = __half22float2(v10.a), c2 = __half22float2(v10.b);
            float2 d  = __half22float2(v11.a), d2 = __half22float2(v11.b);

            f32x4 r;
            r.x = w00 * a.x  + w01 * bb.x + w10 * cc.x + w11 * d.x;
            r.y = w00 * a.y  + w01 * bb.y + w10 * cc.y + w11 * d.y;
            r.z = w00 * a2.x + w01 * b2.x + w10 * c2.x + w11 * d2.x;
            r.w = w00 * a2.y + w01 * b2.y + w10 * c2.y + w11 * d2.y;

            __builtin_nontemporal_store(r, reinterpret_cast<f32x4*>(out + (size_t)sp * 64 + c));
        }
    }
}

// ---------------------------------------------------------------------------
// Overflow drain (direct f32 gather; expected count 0).
// ---------------------------------------------------------------------------
__device__ __forceinline__ void ovf_drain(const float* __restrict__ tp,
                                          const u64* __restrict__ ovf,
                                          const int* __restrict__ ovf_cnt,
                                          float* __restrict__ out)
{
    int grp = threadIdx.x >> 3;
    int t   = threadIdx.x & 7;
    int ocnt = min(*ovf_cnt, OVF_CAP);
    for (int e = grp; e < ocnt; e += 64) {
        u64 rec = ovf[e];
        int sp = (int)(rec >> 40);
        unsigned qx = (unsigned)rec & 0xFFFFFu;
        unsigned qy = (unsigned)(rec >> 20) & 0xFFFFFu;
        int pp = sp - 3 * (sp / 3);

        float ix = (float)qx * (1.0f / 1024.0f) - 0.5f;
        float iy = (float)qy * (1.0f / 1024.0f) - 0.5f;
        int x0 = x0_of_q(qx), y0 = x0_of_q(qy);
        float wx = ix - (float)x0, wy = iy - (float)y0;
        int x1 = x0 + 1, y1 = y0 + 1;

        bool vx0 = ((unsigned)x0 < (unsigned)S);
        bool vx1 = ((unsigned)x1 < (unsigned)S);
        bool vy0 = ((unsigned)y0 < (unsigned)S);
        bool vy1 = ((unsigned)y1 < (unsigned)S);

        float w00 = (vx0 && vy0) ? (1.0f - wy) * (1.0f - wx) : 0.0f;
        float w01 = (vx1 && vy0) ? (1.0f - wy) * wx          : 0.0f;
        float w10 = (vx0 && vy1) ? wy * (1.0f - wx)          : 0.0f;
        float w11 = (vx1 && vy1) ? wy * wx                   : 0.0f;

        int xc0 = min(max(x0, 0), S - 1), xc1 = min(max(x1, 0), S - 1);
        int yc0 = min(max(y0, 0), S - 1), yc1 = min(max(y1, 0), S - 1);

        int o00 = yc0 * S + xc0, o01 = yc0 * S + xc1;
        int o10 = yc1 * S + xc0, o11 = yc1 * S + xc1;

        const float* pb = tp + (size_t)pp * C * (S * S);
        #pragma unroll
        for (int h = 0; h < 2; ++h) {
            float r[4];
            #pragma unroll
            for (int j = 0; j < 4; ++j) {
                const float* ch = pb + (size_t)(4 * t + 32 * h + j) * (S * S);
                r[j] = w00 * ch[o00] + w01 * ch[o01] + w10 * ch[o10] + w11 * ch[o11];
            }
            float4 v = make_float4(r[0], r[1], r[2], r[3]);
            *reinterpret_cast<float4*>(out + (size_t)sp * 64 + 4 * t + 32 * h) = v;
        }
    }
}

// ---------------------------------------------------------------------------
// Cooperative fused kernel: bin own share -> load first halo (overlaps other
// blocks' binning) -> grid.sync -> sample 4 bins.  LDS union: lh/lbase (24KB)
// during binning, halo tile (39.3KB) after.
// ---------------------------------------------------------------------------
__global__ __launch_bounds__(512, 6) void tp_fused(const float* __restrict__ tp,
                                                   const float* __restrict__ coords,
                                                   int total_s, int share,
                                                   int* __restrict__ bincnt,
                                                   u64* __restrict__ slots,
                                                   u64* __restrict__ ovf,
                                                   int* __restrict__ ovf_cnt,
                                                   float* __restrict__ out)
{
    __shared__ __align__(16) unsigned char smem_raw[LDSH * 2];
    int*    lh    = reinterpret_cast<int*>(smem_raw);
    int*    lbase = reinterpret_cast<int*>(smem_raw + NBINS * 4);
    __half* tile  = reinterpret_cast<__half*>(smem_raw);

    int t = threadIdx.x;
    int blk = blockIdx.x;
    int stripe = blk & 7;          // XCD
    int off    = blk >> 3;         // 0..95

    // ---- Binning: this block's sample share (share <= 1024 guaranteed) ----
    for (int i = t; i < NBINS; i += 512) lh[i] = 0;
    __syncthreads();

    int base_s = blk * share;
    int send   = min(base_s + share, total_s);

    int bn [2][3];
    u64 rec[2][3];

    #pragma unroll
    for (int it = 0; it < 2; ++it) {
        int s = base_s + it * 512 + t;
        #pragma unroll
        for (int p = 0; p < 3; ++p) bn[it][p] = -1;
        if (s < send) {
            float cx = coords[3 * s], cy = coords[3 * s + 1], cz = coords[3 * s + 2];
            #pragma unroll
            for (int p = 0; p < 3; ++p) {
                float gx = (p == 2) ? cz : cx;
                float gy = (p == 1) ? cz : cy;
                unsigned qx = quantg(gx), qy = quantg(gy);
                int b = bin_from_q(p, qx, qy);
                bn[it][p]  = b;
                rec[it][p] = ((u64)(3 * s + p) << 40) | ((u64)qy << 20) | qx;
                atomicAdd(&lh[b], 1);
            }
        }
    }
    __syncthreads();
    for (int i = t; i < NBINS; i += 512) {
        int c = lh[i];
        int gb = 0;
        if (c) gb = atomicAdd(&bincnt[i], c);
        lbase[i] = gb;
        lh[i] = 0;
    }
    __syncthreads();
    #pragma unroll
    for (int it = 0; it < 2; ++it) {
        #pragma unroll
        for (int p = 0; p < 3; ++p) {
            int b = bn[it][p];
            if (b >= 0) {
                int r = atomicAdd(&lh[b], 1);
                int slot = lbase[b] + r;
                if (slot < CAP) {
                    slots[(size_t)b * CAP + slot] = rec[it][p];
                } else {
                    int o = atomicAdd(ovf_cnt, 1);
                    if (o < OVF_CAP) ovf[o] = rec[it][p];
                }
            }
        }
    }
    __syncthreads();   // all LDS histogram use done

    // ---- First halo load (overlaps other blocks' binning) ----
    int bin0 = stripe * (NBINS / 8) + off;
    halo_load(tp, bin0, tile);

    // ---- Wait for all binning globally ----
    cg::this_grid().sync();

    // ---- Sample 4 bins ----
    #pragma unroll
    for (int k = 0; k < BINS_PER_BLOCK; ++k) {
        int bin = stripe * (NBINS / 8) + off + k * (GRID_BLOCKS / 8);
        if (k > 0) {
            __syncthreads();           // previous bin's tile reads done
            halo_load(tp, bin, tile);
        }
        __syncthreads();               // tile ready
        int cnt = min(bincnt[bin], CAP);
        sample_bin(bin, cnt, slots + (size_t)bin * CAP, tile, out);
    }

    if (blk == 0) ovf_drain(tp, ovf, ovf_cnt, out);
}

// ===========================================================================
// Fallback two-kernel path (R7-proven): tp_bin + tp_sample_tiled.
// ===========================================================================
constexpr int FB_BIN_IT = 2;   // samples per thread (512 blocks -> 2 blocks/CU)

__global__ __launch_bounds__(512) void tp_bin(const float* __restrict__ coords,
                                              int total_s,
                                              int* __restrict__ bincnt,
                                              u64* __restrict__ slots,
                                              u64* __restrict__ ovf,
                                              int* __restrict__ ovf_cnt)
{
    __shared__ int lh[NBINS];
    __shared__ int lbase[NBINS];
    int t = threadIdx.x;
    for (int i = t; i < NBINS; i += 512) lh[i] = 0;
    __syncthreads();
    int base = blockIdx.x * (512 * FB_BIN_IT);

    int bn [FB_BIN_IT][3];
    u64 rec[FB_BIN_IT][3];

    #pragma unroll
    for (int it = 0; it < FB_BIN_IT; ++it) {
        int s = base + it * 512 + t;
        #pragma unroll
        for (int p = 0; p < 3; ++p) bn[it][p] = -1;
        if (s < total_s) {
            float cx = coords[3 * s], cy = coords[3 * s + 1], cz = coords[3 * s + 2];
            #pragma unroll
            for (int p = 0; p < 3; ++p) {
                float gx = (p == 2) ? cz : cx;
                float gy = (p == 1) ? cz : cy;
                unsigned qx = quantg(gx), qy = quantg(gy);
                int b = bin_from_q(p, qx, qy);
                bn[it][p]  = b;
                rec[it][p] = ((u64)(3 * s + p) << 40) | ((u64)qy << 20) | qx;
                atomicAdd(&lh[b], 1);
            }
        }
    }
    __syncthreads();
    for (int i = t; i < NBINS; i += 512) {
        int c = lh[i];
        int gb = 0;
        if (c) gb = atomicAdd(&bincnt[i], c);
        lbase[i] = gb;
        lh[i] = 0;
    }
    __syncthreads();
    #pragma unroll
    for (int it = 0; it < FB_BIN_IT; ++it) {
        #pragma unroll
        for (int p = 0; p < 3; ++p) {
            int b = bn[it][p];
            if (b >= 0) {
                int r = atomicAdd(&lh[b], 1);
                int slot = lbase[b] + r;
                if (slot < CAP) {
                    slots[(size_t)b * CAP + slot] = rec[it][p];
                } else {
                    int o = atomicAdd(ovf_cnt, 1);
                    if (o < OVF_CAP) ovf[o] = rec[it][p];
                }
            }
        }
    }
}

__global__ __launch_bounds__(512) void tp_sample_tiled(const float* __restrict__ tp,
                                                       const int* __restrict__ bincnt,
                                                       const u64* __restrict__ slots,
                                                       const u64* __restrict__ ovf,
                                                       const int* __restrict__ ovf_cnt,
                                                       float* __restrict__ out)
{
    __shared__ __half tile[LDSH] __attribute__((aligned(16)));

    int b0i = blockIdx.x;
    int b = (b0i & 7) * (NBINS / 8) + (b0i >> 3);   // XCD stripe

    halo_load(tp, b, tile);
    __syncthreads();

    int cnt = min(bincnt[b], CAP);
    sample_bin(b, cnt, slots + (size_t)b * CAP, tile, out);

    if (b0i == 0) ovf_drain(tp, ovf, ovf_cnt, out);
}

// ---------------------------------------------------------------------------
// Full fallback: direct gather (only if ws is too small for the binned path).
// ---------------------------------------------------------------------------
__global__ __launch_bounds__(256) void tp_sample_direct(const float* __restrict__ coords,
                                                        const float* __restrict__ tp,
                                                        float* __restrict__ out,
                                                        int total_sp)
{
    int tid = blockIdx.x * 256 + threadIdx.x;
    int gi = tid >> 4;
    if (gi >= total_sp) return;
    int t = tid & 15;

    int s = gi / 3;
    int p = gi - 3 * s;
    float cx = coords[3 * s], cy = coords[3 * s + 1], cz = coords[3 * s + 2];
    float gx = (p == 2) ? cz : cx;
    float gy = (p == 1) ? cz : cy;
    float ix = (gx + 1.0f) * 256.0f - 0.5f;
    float iy = (gy + 1.0f) * 256.0f - 0.5f;

    float x0f = floorf(ix), y0f = floorf(iy);
    float wx = ix - x0f, wy = iy - y0f;
    int x0 = (int)x0f, y0 = (int)y0f;
    int x1 = x0 + 1,   y1 = y0 + 1;

    bool vx0 = ((unsigned)x0 < (unsigned)S);
    bool vx1 = ((unsigned)x1 < (unsigned)S);
    bool vy0 = ((unsigned)y0 < (unsigned)S);
    bool vy1 = ((unsigned)y1 < (unsigned)S);

    float w00 = (vx0 && vy0) ? (1.0f - wy) * (1.0f - wx) : 0.0f;
    float w01 = (vx1 && vy0) ? (1.0f - wy) * wx          : 0.0f;
    float w10 = (vx0 && vy1) ? wy * (1.0f - wx)          : 0.0f;
    float w11 = (vx1 && vy1) ? wy * wx                   : 0.0f;

    int xc0 = min(max(x0, 0), S - 1), xc1 = min(max(x1, 0), S - 1);
    int yc0 = min(max(y0, 0), S - 1), yc1 = min(max(y1, 0), S - 1);

    int o00 = yc0 * S + xc0, o01 = yc0 * S + xc1;
    int o10 = yc1 * S + xc0, o11 = yc1 * S + xc1;

    const float* pb = tp + (size_t)p * C * (S * S);
    float r[4];
    #pragma unroll
    for (int j = 0; j < 4; ++j) {
        const float* ch = pb + (size_t)(4 * t + j) * (S * S);
        r[j] = w00 * ch[o00] + w01 * ch[o01] + w10 * ch[o10] + w11 * ch[o11];
    }
    float4 v = make_float4(r[0], r[1], r[2], r[3]);
    *reinterpret_cast<float4*>(out + (size_t)gi * 64 + 4 * t) = v;
}

} // namespace

extern "C" void kernel_launch(void* const* d_in, const int* in_sizes, int n_in,
                              void* d_out, int out_size, void* d_ws, size_t ws_size,
                              hipStream_t stream)
{
    const float* coords  = (const float*)d_in[0];  // (N, M, 3) f32
    const float* tplanes = (const float*)d_in[1];  // (1, 3, C, S, S) f32
    float* out = (float*)d_out;                    // (N, M, 3*C) f32

    int total_sp = in_sizes[0];                    // N*M*3
    int total_s  = total_sp / 3;                   // N*M samples

    // ws layout: bincnt[3072] | ovf_cnt | pad | ovf[8192] u64 | slots[3072*CAP] u64
    const size_t bincntOff = 0;
    const size_t ovfcntOff = (size_t)NBINS * 4;            // 12288
    const size_t ovfOff    = 12352;
    const size_t slotsOff  = ovfOff + (size_t)OVF_CAP * 8; // 77888
    const size_t need      = slotsOff + (size_t)NBINS * CAP * 8;  // ~18.4 MB

    if (ws_size >= need) {
        int* bincnt  = (int*)((char*)d_ws + bincntOff);
        int* ovf_cnt = (int*)((char*)d_ws + ovfcntOff);
        u64* ovf     = (u64*)((char*)d_ws + ovfOff);
        u64* slots   = (u64*)((char*)d_ws + slotsOff);

        hipMemsetAsync(d_ws, 0, ovfcntOff + 64, stream);   // bincnt + ovf_cnt

        int share = (total_s + GRID_BLOCKS - 1) / GRID_BLOCKS;
        bool coop_ok = (share <= 1024);

        hipError_t e = hipErrorUnknown;
        if (coop_ok) {
            void* args[] = { (void*)&tplanes, (void*)&coords, (void*)&total_s,
                             (void*)&share, (void*)&bincnt, (void*)&slots,
                             (void*)&ovf, (void*)&ovf_cnt, (void*)&out };
            e = hipLaunchCooperativeKernel((const void*)tp_fused,
                                           dim3(GRID_BLOCKS), dim3(512),
                                           args, 0, stream);
        }
        if (e != hipSuccess) {
            // Fallback: proven two-kernel path.
            int nb_bin = (total_s + 512 * FB_BIN_IT - 1) / (512 * FB_BIN_IT);
            tp_bin<<<nb_bin, 512, 0, stream>>>(coords, total_s, bincnt, slots, ovf, ovf_cnt);
            tp_sample_tiled<<<NBINS, 512, 0, stream>>>(tplanes, bincnt, slots,
                                                       ovf, ovf_cnt, out);
        }
    } else {
        int nb_sm = (total_sp * 16 + 255) / 256;
        tp_sample_direct<<<nb_sm, 256, 0, stream>>>(coords, tplanes, out, total_sp);
    }
}

// Round 10
// 143.156 us; speedup vs baseline: 1.9736x; 1.9736x over previous
//
#include <hip/hip_runtime.h>
#include <hip/hip_fp16.h>

namespace {

constexpr int S = 512;        // plane height/width
constexpr int C = 64;         // channels per plane
constexpr int TILE = 16;      // texel tile side
constexpr int TPP  = 32;      // tiles per plane side (512/16)
constexpr int NBINS = 3 * TPP * TPP;   // 3072 bins = (plane, ty, tx)
constexpr int CAP = 744;      // slots per bin (lambda=512, +10 sigma)
constexpr int OVF_CAP = 8192; // overflow list capacity
constexpr int BIN_IT = 2;     // samples per thread in tp_bin (512 blocks, 2/CU)

constexpr int HH = 17;        // halo rows
constexpr int HW = 17;        // halo cols
constexpr int TSTRIDE = 68;   // halves per texel slot (136B; 8B-aligned)
constexpr int LDSH = HH * HW * TSTRIDE;  // 19652 halves = 39304 B -> 4 blocks/CU

typedef float f32x4 __attribute__((ext_vector_type(4)));
struct alignas(8) H4 { __half2 a, b; };
typedef unsigned long long u64;

// q = floor((g+1)*262144)  ->  ix_q = q/1024 - 0.5, error <= 1/1024 texel,
// floor-consistent: x0 = (q-512)>>10 == floor(ix) for in-range inputs.
__device__ __forceinline__ unsigned quantg(float g)
{
    float v = (g + 1.0f) * 262144.0f;
    int q = (int)floorf(v);
    q = min(max(q, 0), 1048575);          // pack-safe clamp (inputs are [-1,1])
    return (unsigned)q;
}

__device__ __forceinline__ int x0_of_q(unsigned q) { return ((int)q - 512) >> 10; }

__device__ __forceinline__ int bin_from_q(int p, unsigned qx, unsigned qy)
{
    int xc0 = min(max(x0_of_q(qx), 0), S - 1);
    int yc0 = min(max(x0_of_q(qy), 0), S - 1);
    return p * (TPP * TPP) + (yc0 >> 4) * TPP + (xc0 >> 4);
}

// ---------------------------------------------------------------------------
// Single-pass binning: 512 thr x BIN_IT samples; each sample -> 3 records.
// Coords read ONCE; bn + packed record carried in registers across the two
// LDS-aggregation phases.  Record: sp(24b) | qy(20b) | qx(20b).
// ---------------------------------------------------------------------------
__global__ __launch_bounds__(512) void tp_bin(const float* __restrict__ coords,
                                              int total_s,
                                              int* __restrict__ bincnt,
                                              u64* __restrict__ slots,
                                              u64* __restrict__ ovf,
                                              int* __restrict__ ovf_cnt)
{
    __shared__ int lh[NBINS];
    __shared__ int lbase[NBINS];
    int t = threadIdx.x;
    for (int i = t; i < NBINS; i += 512) lh[i] = 0;
    __syncthreads();
    int base = blockIdx.x * (512 * BIN_IT);

    int bn [BIN_IT][3];
    u64 rec[BIN_IT][3];

    // pass A: project once, local histogram
    #pragma unroll
    for (int it = 0; it < BIN_IT; ++it) {
        int s = base + it * 512 + t;
        #pragma unroll
        for (int p = 0; p < 3; ++p) bn[it][p] = -1;
        if (s < total_s) {
            float cx = coords[3 * s], cy = coords[3 * s + 1], cz = coords[3 * s + 2];
            #pragma unroll
            for (int p = 0; p < 3; ++p) {
                float gx = (p == 2) ? cz : cx;
                float gy = (p == 1) ? cz : cy;
                unsigned qx = quantg(gx), qy = quantg(gy);
                int b = bin_from_q(p, qx, qy);
                bn[it][p]  = b;
                rec[it][p] = ((u64)(3 * s + p) << 40) | ((u64)qy << 20) | qx;
                atomicAdd(&lh[b], 1);
            }
        }
    }
    __syncthreads();
    // merged: reserve global chunk + reset lh in one sweep
    for (int i = t; i < NBINS; i += 512) {
        int c = lh[i];
        int gb = 0;
        if (c) gb = atomicAdd(&bincnt[i], c);
        lbase[i] = gb;
        lh[i] = 0;
    }
    __syncthreads();

    // pass B: allocate slot, write record
    #pragma unroll
    for (int it = 0; it < BIN_IT; ++it) {
        #pragma unroll
        for (int p = 0; p < 3; ++p) {
            int b = bn[it][p];
            if (b >= 0) {
                int r = atomicAdd(&lh[b], 1);
                int slot = lbase[b] + r;
                if (slot < CAP) {
                    slots[(size_t)b * CAP + slot] = rec[it][p];
                } else {
                    int o = atomicAdd(ovf_cnt, 1);
                    if (o < OVF_CAP) ovf[o] = rec[it][p];
                }
            }
        }
    }
}

// ---------------------------------------------------------------------------
// Fused tile sampler: one 512-thread block per bin (XCD-striped bin order).
// Phase 1: 17x17-texel halo x 64ch, channel-major f32 -> LDS f16 (136B texel
//          stride).  Phase 2: 8 lanes/sample, H4 LDS corner reads at
//          c = 4t and 32+4t, bilinear blend, two 128B-group-contiguous
//          nontemporal f32x4 stores; unroll-2 for 2 independent sample
//          chains in flight.  Block b0i==0 drains the overflow list.
// ---------------------------------------------------------------------------
__global__ __launch_bounds__(512) void tp_sample_tiled(const float* __restrict__ tp,
                                                       const int* __restrict__ bincnt,
                                                       const u64* __restrict__ slots,
                                                       const u64* __restrict__ ovf,
                                                       const int* __restrict__ ovf_cnt,
                                                       float* __restrict__ out)
{
    __shared__ __half tile[LDSH] __attribute__((aligned(16)));

    int b0i = blockIdx.x;
    int b = (b0i & 7) * (NBINS / 8) + (b0i >> 3);   // XCD stripe

    int p  = b >> 10;
    int ty = (b >> 5) & 31;
    int tx = b & 31;
    int xg = tx * TILE;
    int yg = ty * TILE;

    const float* pl = tp + (size_t)p * C * (S * S);

    // ---- Phase 1: halo load.  tasks = 64ch x 17rows x 5 x-segments ----
    for (int task = threadIdx.x; task < C * HH * 5; task += 512) {
        int seg = task % 5;
        int rem = task / 5;
        int row = rem % HH;
        int ch  = rem / HH;
        int y   = min(yg + row, S - 1);
        int cb  = (seg < 4) ? seg * 4 : 13;
        int xb  = xg + cb;
        if (xb > S - 4) xb = S - 4;            // only tx=31, seg 4
        float4 v = *reinterpret_cast<const float4*>(pl + ((size_t)ch * S + y) * S + xb);
        __half* trow = &tile[(row * HW) * TSTRIDE + ch];
        #pragma unroll
        for (int i = 0; i < 4; ++i) {
            int col = xb + i - xg;
            if (col >= 0 && col < HW)
                trow[col * TSTRIDE] = __float2half(((const float*)&v)[i]);
        }
        if (xb != xg + cb)                      // tx=31: col 16 (weight-dead)
            trow[16 * TSTRIDE] = __float2half(((const float*)&v)[3]);
    }
    __syncthreads();

    // ---- Phase 2: sample (64 groups of 8 lanes) ----
    int cnt = min(bincnt[b], CAP);
    const u64* sb = slots + (size_t)b * CAP;
    int grp = threadIdx.x >> 3;
    int t   = threadIdx.x & 7;

    #pragma unroll 2
    for (int gi = grp; gi < cnt; gi += 64) {
        u64 rec = sb[gi];
        int sp = (int)(rec >> 40);
        unsigned qx = (unsigned)rec & 0xFFFFFu;
        unsigned qy = (unsigned)(rec >> 20) & 0xFFFFFu;

        float ix = (float)qx * (1.0f / 1024.0f) - 0.5f;
        float iy = (float)qy * (1.0f / 1024.0f) - 0.5f;
        int x0 = x0_of_q(qx), y0 = x0_of_q(qy);
        float wx = ix - (float)x0, wy = iy - (float)y0;
        int x1 = x0 + 1, y1 = y0 + 1;

        bool vx0 = ((unsigned)x0 < (unsigned)S);
        bool vx1 = ((unsigned)x1 < (unsigned)S);
        bool vy0 = ((unsigned)y0 < (unsigned)S);
        bool vy1 = ((unsigned)y1 < (unsigned)S);

        float w00 = (vx0 && vy0) ? (1.0f - wy) * (1.0f - wx) : 0.0f;
        float w01 = (vx1 && vy0) ? (1.0f - wy) * wx          : 0.0f;
        float w10 = (vx0 && vy1) ? wy * (1.0f - wx)          : 0.0f;
        float w11 = (vx1 && vy1) ? wy * wx                   : 0.0f;

        int lx0 = min(max(x0, 0), S - 1) - xg;
        int lx1 = min(max(x1, 0), S - 1) - xg;
        int ly0 = min(max(y0, 0), S - 1) - yg;
        int ly1 = min(max(y1, 0), S - 1) - yg;

        int o00 = (ly0 * HW + lx0) * TSTRIDE;
        int o01 = (ly0 * HW + lx1) * TSTRIDE;
        int o10 = (ly1 * HW + lx0) * TSTRIDE;
        int o11 = (ly1 * HW + lx1) * TSTRIDE;

        #pragma unroll
        for (int h = 0; h < 2; ++h) {
            int c = 4 * t + 32 * h;
            H4 v00 = *reinterpret_cast<const H4*>(&tile[o00 + c]);
            H4 v01 = *reinterpret_cast<const H4*>(&tile[o01 + c]);
            H4 v10 = *reinterpret_cast<const H4*>(&tile[o10 + c]);
            H4 v11 = *reinterpret_cast<const H4*>(&tile[o11 + c]);

            float2 a  = __half22float2(v00.a), a2 = __half22float2(v00.b);
            float2 bb = __half22float2(v01.a), b2 = __half22float2(v01.b);
            float2 cc = __half22float2(v10.a), c2 = __half22float2(v10.b);
            float2 d  = __half22float2(v11.a), d2 = __half22float2(v11.b);

            f32x4 r;
            r.x = w00 * a.x  + w01 * bb.x + w10 * cc.x + w11 * d.x;
            r.y = w00 * a.y  + w01 * bb.y + w10 * cc.y + w11 * d.y;
            r.z = w00 * a2.x + w01 * b2.x + w10 * c2.x + w11 * d2.x;
            r.w = w00 * a2.y + w01 * b2.y + w10 * c2.y + w11 * d2.y;

            __builtin_nontemporal_store(r, reinterpret_cast<f32x4*>(out + (size_t)sp * 64 + c));
        }
    }

    // ---- Overflow drain (block 0 only; expected count 0) ----
    if (b0i == 0) {
        int ocnt = min(*ovf_cnt, OVF_CAP);
        for (int e = grp; e < ocnt; e += 64) {
            u64 rec = ovf[e];
            int sp = (int)(rec >> 40);
            unsigned qx = (unsigned)rec & 0xFFFFFu;
            unsigned qy = (unsigned)(rec >> 20) & 0xFFFFFu;
            int pp = sp - 3 * (sp / 3);

            float ix = (float)qx * (1.0f / 1024.0f) - 0.5f;
            float iy = (float)qy * (1.0f / 1024.0f) - 0.5f;
            int x0 = x0_of_q(qx), y0 = x0_of_q(qy);
            float wx = ix - (float)x0, wy = iy - (float)y0;
            int x1 = x0 + 1, y1 = y0 + 1;

            bool vx0 = ((unsigned)x0 < (unsigned)S);
            bool vx1 = ((unsigned)x1 < (unsigned)S);
            bool vy0 = ((unsigned)y0 < (unsigned)S);
            bool vy1 = ((unsigned)y1 < (unsigned)S);

            float w00 = (vx0 && vy0) ? (1.0f - wy) * (1.0f - wx) : 0.0f;
            float w01 = (vx1 && vy0) ? (1.0f - wy) * wx          : 0.0f;
            float w10 = (vx0 && vy1) ? wy * (1.0f - wx)          : 0.0f;
            float w11 = (vx1 && vy1) ? wy * wx                   : 0.0f;

            int xc0 = min(max(x0, 0), S - 1), xc1 = min(max(x1, 0), S - 1);
            int yc0 = min(max(y0, 0), S - 1), yc1 = min(max(y1, 0), S - 1);

            int o00 = yc0 * S + xc0, o01 = yc0 * S + xc1;
            int o10 = yc1 * S + xc0, o11 = yc1 * S + xc1;

            const float* pb = tp + (size_t)pp * C * (S * S);
            #pragma unroll
            for (int h = 0; h < 2; ++h) {
                float r[4];
                #pragma unroll
                for (int j = 0; j < 4; ++j) {
                    const float* ch = pb + (size_t)(4 * t + 32 * h + j) * (S * S);
                    r[j] = w00 * ch[o00] + w01 * ch[o01] + w10 * ch[o10] + w11 * ch[o11];
                }
                float4 v = make_float4(r[0], r[1], r[2], r[3]);
                *reinterpret_cast<float4*>(out + (size_t)sp * 64 + 4 * t + 32 * h) = v;
            }
        }
    }
}

// ---------------------------------------------------------------------------
// Full fallback: direct gather (only if ws is too small for the binned path).
// ---------------------------------------------------------------------------
__global__ __launch_bounds__(256) void tp_sample_direct(const float* __restrict__ coords,
                                                        const float* __restrict__ tp,
                                                        float* __restrict__ out,
                                                        int total_sp)
{
    int tid = blockIdx.x * 256 + threadIdx.x;
    int gi = tid >> 4;
    if (gi >= total_sp) return;
    int t = tid & 15;

    int s = gi / 3;
    int p = gi - 3 * s;
    float cx = coords[3 * s], cy = coords[3 * s + 1], cz = coords[3 * s + 2];
    float gx = (p == 2) ? cz : cx;
    float gy = (p == 1) ? cz : cy;
    float ix = (gx + 1.0f) * 256.0f - 0.5f;
    float iy = (gy + 1.0f) * 256.0f - 0.5f;

    float x0f = floorf(ix), y0f = floorf(iy);
    float wx = ix - x0f, wy = iy - y0f;
    int x0 = (int)x0f, y0 = (int)y0f;
    int x1 = x0 + 1,   y1 = y0 + 1;

    bool vx0 = ((unsigned)x0 < (unsigned)S);
    bool vx1 = ((unsigned)x1 < (unsigned)S);
    bool vy0 = ((unsigned)y0 < (unsigned)S);
    bool vy1 = ((unsigned)y1 < (unsigned)S);

    float w00 = (vx0 && vy0) ? (1.0f - wy) * (1.0f - wx) : 0.0f;
    float w01 = (vx1 && vy0) ? (1.0f - wy) * wx          : 0.0f;
    float w10 = (vx0 && vy1) ? wy * (1.0f - wx)          : 0.0f;
    float w11 = (vx1 && vy1) ? wy * wx                   : 0.0f;

    int xc0 = min(max(x0, 0), S - 1), xc1 = min(max(x1, 0), S - 1);
    int yc0 = min(max(y0, 0), S - 1), yc1 = min(max(y1, 0), S - 1);

    int o00 = yc0 * S + xc0, o01 = yc0 * S + xc1;
    int o10 = yc1 * S + xc0, o11 = yc1 * S + xc1;

    const float* pb = tp + (size_t)p * C * (S * S);
    float r[4];
    #pragma unroll
    for (int j = 0; j < 4; ++j) {
        const float* ch = pb + (size_t)(4 * t + j) * (S * S);
        r[j] = w00 * ch[o00] + w01 * ch[o01] + w10 * ch[o10] + w11 * ch[o11];
    }
    float4 v = make_float4(r[0], r[1], r[2], r[3]);
    *reinterpret_cast<float4*>(out + (size_t)gi * 64 + 4 * t) = v;
}

} // namespace

extern "C" void kernel_launch(void* const* d_in, const int* in_sizes, int n_in,
                              void* d_out, int out_size, void* d_ws, size_t ws_size,
                              hipStream_t stream)
{
    const float* coords  = (const float*)d_in[0];  // (N, M, 3) f32
    const float* tplanes = (const float*)d_in[1];  // (1, 3, C, S, S) f32
    float* out = (float*)d_out;                    // (N, M, 3*C) f32

    int total_sp = in_sizes[0];                    // N*M*3
    int total_s  = total_sp / 3;                   // N*M samples

    // ws layout: bincnt[3072] | ovf_cnt | pad | ovf[8192] u64 | slots[3072*CAP] u64
    const size_t bincntOff = 0;
    const size_t ovfcntOff = (size_t)NBINS * 4;            // 12288
    const size_t ovfOff    = 12352;
    const size_t slotsOff  = ovfOff + (size_t)OVF_CAP * 8; // 77888
    const size_t need      = slotsOff + (size_t)NBINS * CAP * 8;  // ~18.4 MB

    if (ws_size >= need) {
        int* bincnt  = (int*)((char*)d_ws + bincntOff);
        int* ovf_cnt = (int*)((char*)d_ws + ovfcntOff);
        u64* ovf     = (u64*)((char*)d_ws + ovfOff);
        u64* slots   = (u64*)((char*)d_ws + slotsOff);

        int nb_bin = (total_s + 512 * BIN_IT - 1) / (512 * BIN_IT);

        hipMemsetAsync(d_ws, 0, ovfcntOff + 64, stream);   // bincnt + ovf_cnt
        tp_bin<<<nb_bin, 512, 0, stream>>>(coords, total_s, bincnt, slots, ovf, ovf_cnt);
        tp_sample_tiled<<<NBINS, 512, 0, stream>>>(tplanes, bincnt, slots,
                                                   ovf, ovf_cnt, out);
    } else {
        int nb_sm = (total_sp * 16 + 255) / 256;
        tp_sample_direct<<<nb_sm, 256, 0, stream>>>(coords, tplanes, out, total_sp);
    }
}

// Round 11
// 133.108 us; speedup vs baseline: 2.1226x; 1.0755x over previous
//
#include <hip/hip_runtime.h>
#include <hip/hip_fp16.h>

namespace {

constexpr int S = 512;        // plane height/width
constexpr int C = 64;         // channels per plane
constexpr int TILE = 16;      // texel tile side
constexpr int TPP  = 32;      // tiles per plane side (512/16)
constexpr int NBINS = 3 * TPP * TPP;   // 3072 bins = (plane, ty, tx)
constexpr int CAP = 744;      // slots per bin (lambda=512, +10 sigma)
constexpr int OVF_CAP = 8192; // overflow list capacity
constexpr int BIN_IT = 4;     // samples per thread in tp_bin (256 blocks)

constexpr int HH = 17;        // halo rows
constexpr int HW = 17;        // halo cols
constexpr int TSTRIDE = 68;   // halves per texel slot (136B; 8B-aligned)
constexpr int LDSH = HH * HW * TSTRIDE;  // 19652 halves = 39304 B -> 4 blocks/CU

typedef float f32x4 __attribute__((ext_vector_type(4)));
struct alignas(8) H4 { __half2 a, b; };
typedef unsigned long long u64;

// q = floor((g+1)*262144)  ->  ix_q = q/1024 - 0.5, error <= 1/1024 texel,
// floor-consistent: x0 = (q-512)>>10 == floor(ix) for in-range inputs.
__device__ __forceinline__ unsigned quantg(float g)
{
    float v = (g + 1.0f) * 262144.0f;
    int q = (int)floorf(v);
    q = min(max(q, 0), 1048575);          // pack-safe clamp (inputs are [-1,1])
    return (unsigned)q;
}

__device__ __forceinline__ int x0_of_q(unsigned q) { return ((int)q - 512) >> 10; }

__device__ __forceinline__ int bin_from_q(int p, unsigned qx, unsigned qy)
{
    int xc0 = min(max(x0_of_q(qx), 0), S - 1);
    int yc0 = min(max(x0_of_q(qy), 0), S - 1);
    return p * (TPP * TPP) + (yc0 >> 4) * TPP + (xc0 >> 4);
}

// ---------------------------------------------------------------------------
// Single-pass binning: 512 thr x BIN_IT samples; each sample -> 3 records.
// Coords read ONCE; bn + packed record carried in registers across the
// two LDS-aggregation phases.  Record: sp(24b) | qy(20b) | qx(20b).
// ---------------------------------------------------------------------------
__global__ __launch_bounds__(512) void tp_bin(const float* __restrict__ coords,
                                              int total_s,
                                              int* __restrict__ bincnt,
                                              u64* __restrict__ slots,
                                              u64* __restrict__ ovf,
                                              int* __restrict__ ovf_cnt)
{
    __shared__ int lh[NBINS];
    __shared__ int lbase[NBINS];
    int t = threadIdx.x;
    for (int i = t; i < NBINS; i += 512) lh[i] = 0;
    __syncthreads();
    int base = blockIdx.x * (512 * BIN_IT);

    int  bn [BIN_IT][3];
    u64  rec[BIN_IT][3];

    // pass A: project once, local histogram
    #pragma unroll
    for (int it = 0; it < BIN_IT; ++it) {
        int s = base + it * 512 + t;
        #pragma unroll
        for (int p = 0; p < 3; ++p) bn[it][p] = -1;
        if (s < total_s) {
            float cx = coords[3 * s], cy = coords[3 * s + 1], cz = coords[3 * s + 2];
            #pragma unroll
            for (int p = 0; p < 3; ++p) {
                float gx = (p == 2) ? cz : cx;
                float gy = (p == 1) ? cz : cy;
                unsigned qx = quantg(gx), qy = quantg(gy);
                int b = bin_from_q(p, qx, qy);
                bn[it][p]  = b;
                rec[it][p] = ((u64)(3 * s + p) << 40) | ((u64)qy << 20) | qx;
                atomicAdd(&lh[b], 1);
            }
        }
    }
    __syncthreads();
    for (int i = t; i < NBINS; i += 512) {
        int c = lh[i];
        if (c) lbase[i] = atomicAdd(&bincnt[i], c);
    }
    __syncthreads();
    for (int i = t; i < NBINS; i += 512) lh[i] = 0;
    __syncthreads();

    // pass B: allocate slot, write record
    #pragma unroll
    for (int it = 0; it < BIN_IT; ++it) {
        #pragma unroll
        for (int p = 0; p < 3; ++p) {
            int b = bn[it][p];
            if (b >= 0) {
                int r = atomicAdd(&lh[b], 1);
                int slot = lbase[b] + r;
                if (slot < CAP) {
                    slots[(size_t)b * CAP + slot] = rec[it][p];
                } else {
                    int o = atomicAdd(ovf_cnt, 1);
                    if (o < OVF_CAP) ovf[o] = rec[it][p];
                }
            }
        }
    }
}

// ---------------------------------------------------------------------------
// Fused tile sampler: one 512-thread block per bin (XCD-striped bin order).
// Phase 1: 17x17-texel halo x 64ch, channel-major f32 -> LDS f16 (136B texel
//          stride).  Phase 2: 8 lanes/sample, H4 LDS corner reads at
//          c = 4t and 32+4t, bilinear blend, two 128B-group-contiguous
//          nontemporal f32x4 stores.  Block b0i==0 additionally drains the
//          (practically empty) overflow list with direct f32 gathers.
// ---------------------------------------------------------------------------
__global__ __launch_bounds__(512) void tp_sample_tiled(const float* __restrict__ tp,
                                                       const int* __restrict__ bincnt,
                                                       const u64* __restrict__ slots,
                                                       const u64* __restrict__ ovf,
                                                       const int* __restrict__ ovf_cnt,
                                                       float* __restrict__ out)
{
    __shared__ __half tile[LDSH] __attribute__((aligned(16)));

    int b0i = blockIdx.x;
    int b = (b0i & 7) * (NBINS / 8) + (b0i >> 3);   // XCD stripe

    int p  = b >> 10;
    int ty = (b >> 5) & 31;
    int tx = b & 31;
    int xg = tx * TILE;
    int yg = ty * TILE;

    const float* pl = tp + (size_t)p * C * (S * S);

    // ---- Phase 1: halo load.  tasks = 64ch x 17rows x 5 x-segments ----
    for (int task = threadIdx.x; task < C * HH * 5; task += 512) {
        int seg = task % 5;
        int rem = task / 5;
        int row = rem % HH;
        int ch  = rem / HH;
        int y   = min(yg + row, S - 1);
        int cb  = (seg < 4) ? seg * 4 : 13;
        int xb  = xg + cb;
        if (xb > S - 4) xb = S - 4;            // only tx=31, seg 4
        float4 v = *reinterpret_cast<const float4*>(pl + ((size_t)ch * S + y) * S + xb);
        __half* trow = &tile[(row * HW) * TSTRIDE + ch];
        #pragma unroll
        for (int i = 0; i < 4; ++i) {
            int col = xb + i - xg;
            if (col >= 0 && col < HW)
                trow[col * TSTRIDE] = __float2half(((const float*)&v)[i]);
        }
        if (xb != xg + cb)                      // tx=31: col 16 (weight-dead)
            trow[16 * TSTRIDE] = __float2half(((const float*)&v)[3]);
    }
    __syncthreads();

    // ---- Phase 2: sample (64 groups of 8 lanes) ----
    int cnt = min(bincnt[b], CAP);
    const u64* sb = slots + (size_t)b * CAP;
    int grp = threadIdx.x >> 3;
    int t   = threadIdx.x & 7;

    for (int gi = grp; gi < cnt; gi += 64) {
        u64 rec = sb[gi];
        int sp = (int)(rec >> 40);
        unsigned qx = (unsigned)rec & 0xFFFFFu;
        unsigned qy = (unsigned)(rec >> 20) & 0xFFFFFu;

        float ix = (float)qx * (1.0f / 1024.0f) - 0.5f;
        float iy = (float)qy * (1.0f / 1024.0f) - 0.5f;
        int x0 = x0_of_q(qx), y0 = x0_of_q(qy);
        float wx = ix - (float)x0, wy = iy - (float)y0;
        int x1 = x0 + 1, y1 = y0 + 1;

        bool vx0 = ((unsigned)x0 < (unsigned)S);
        bool vx1 = ((unsigned)x1 < (unsigned)S);
        bool vy0 = ((unsigned)y0 < (unsigned)S);
        bool vy1 = ((unsigned)y1 < (unsigned)S);

        float w00 = (vx0 && vy0) ? (1.0f - wy) * (1.0f - wx) : 0.0f;
        float w01 = (vx1 && vy0) ? (1.0f - wy) * wx          : 0.0f;
        float w10 = (vx0 && vy1) ? wy * (1.0f - wx)          : 0.0f;
        float w11 = (vx1 && vy1) ? wy * wx                   : 0.0f;

        int lx0 = min(max(x0, 0), S - 1) - xg;
        int lx1 = min(max(x1, 0), S - 1) - xg;
        int ly0 = min(max(y0, 0), S - 1) - yg;
        int ly1 = min(max(y1, 0), S - 1) - yg;

        int o00 = (ly0 * HW + lx0) * TSTRIDE;
        int o01 = (ly0 * HW + lx1) * TSTRIDE;
        int o10 = (ly1 * HW + lx0) * TSTRIDE;
        int o11 = (ly1 * HW + lx1) * TSTRIDE;

        #pragma unroll
        for (int h = 0; h < 2; ++h) {
            int c = 4 * t + 32 * h;
            H4 v00 = *reinterpret_cast<const H4*>(&tile[o00 + c]);
            H4 v01 = *reinterpret_cast<const H4*>(&tile[o01 + c]);
            H4 v10 = *reinterpret_cast<const H4*>(&tile[o10 + c]);
            H4 v11 = *reinterpret_cast<const H4*>(&tile[o11 + c]);

            float2 a  = __half22float2(v00.a), a2 = __half22float2(v00.b);
            float2 bb = __half22float2(v01.a), b2 = __half22float2(v01.b);
            float2 cc = __half22float2(v10.a), c2 = __half22float2(v10.b);
            float2 d  = __half22float2(v11.a), d2 = __half22float2(v11.b);

            f32x4 r;
            r.x = w00 * a.x  + w01 * bb.x + w10 * cc.x + w11 * d.x;
            r.y = w00 * a.y  + w01 * bb.y + w10 * cc.y + w11 * d.y;
            r.z = w00 * a2.x + w01 * b2.x + w10 * c2.x + w11 * d2.x;
            r.w = w00 * a2.y + w01 * b2.y + w10 * c2.y + w11 * d2.y;

            __builtin_nontemporal_store(r, reinterpret_cast<f32x4*>(out + (size_t)sp * 64 + c));
        }
    }

    // ---- Overflow drain (block 0 only; expected count 0) ----
    if (b0i == 0) {
        int ocnt = min(*ovf_cnt, OVF_CAP);
        for (int e = grp; e < ocnt; e += 64) {
            u64 rec = ovf[e];
            int sp = (int)(rec >> 40);
            unsigned qx = (unsigned)rec & 0xFFFFFu;
            unsigned qy = (unsigned)(rec >> 20) & 0xFFFFFu;
            int pp = sp - 3 * (sp / 3);

            float ix = (float)qx * (1.0f / 1024.0f) - 0.5f;
            float iy = (float)qy * (1.0f / 1024.0f) - 0.5f;
            int x0 = x0_of_q(qx), y0 = x0_of_q(qy);
            float wx = ix - (float)x0, wy = iy - (float)y0;
            int x1 = x0 + 1, y1 = y0 + 1;

            bool vx0 = ((unsigned)x0 < (unsigned)S);
            bool vx1 = ((unsigned)x1 < (unsigned)S);
            bool vy0 = ((unsigned)y0 < (unsigned)S);
            bool vy1 = ((unsigned)y1 < (unsigned)S);

            float w00 = (vx0 && vy0) ? (1.0f - wy) * (1.0f - wx) : 0.0f;
            float w01 = (vx1 && vy0) ? (1.0f - wy) * wx          : 0.0f;
            float w10 = (vx0 && vy1) ? wy * (1.0f - wx)          : 0.0f;
            float w11 = (vx1 && vy1) ? wy * wx                   : 0.0f;

            int xc0 = min(max(x0, 0), S - 1), xc1 = min(max(x1, 0), S - 1);
            int yc0 = min(max(y0, 0), S - 1), yc1 = min(max(y1, 0), S - 1);

            int o00 = yc0 * S + xc0, o01 = yc0 * S + xc1;
            int o10 = yc1 * S + xc0, o11 = yc1 * S + xc1;

            const float* pb = tp + (size_t)pp * C * (S * S);
            #pragma unroll
            for (int h = 0; h < 2; ++h) {
                float r[4];
                #pragma unroll
                for (int j = 0; j < 4; ++j) {
                    const float* ch = pb + (size_t)(4 * t + 32 * h + j) * (S * S);
                    r[j] = w00 * ch[o00] + w01 * ch[o01] + w10 * ch[o10] + w11 * ch[o11];
                }
                float4 v = make_float4(r[0], r[1], r[2], r[3]);
                *reinterpret_cast<float4*>(out + (size_t)sp * 64 + 4 * t + 32 * h) = v;
            }
        }
    }
}

// ---------------------------------------------------------------------------
// Full fallback: direct gather (only if ws is too small for the binned path).
// ---------------------------------------------------------------------------
__global__ __launch_bounds__(256) void tp_sample_direct(const float* __restrict__ coords,
                                                        const float* __restrict__ tp,
                                                        float* __restrict__ out,
                                                        int total_sp)
{
    int tid = blockIdx.x * 256 + threadIdx.x;
    int gi = tid >> 4;
    if (gi >= total_sp) return;
    int t = tid & 15;

    int s = gi / 3;
    int p = gi - 3 * s;
    float cx = coords[3 * s], cy = coords[3 * s + 1], cz = coords[3 * s + 2];
    float gx = (p == 2) ? cz : cx;
    float gy = (p == 1) ? cz : cy;
    float ix = (gx + 1.0f) * 256.0f - 0.5f;
    float iy = (gy + 1.0f) * 256.0f - 0.5f;

    float x0f = floorf(ix), y0f = floorf(iy);
    float wx = ix - x0f, wy = iy - y0f;
    int x0 = (int)x0f, y0 = (int)y0f;
    int x1 = x0 + 1,   y1 = y0 + 1;

    bool vx0 = ((unsigned)x0 < (unsigned)S);
    bool vx1 = ((unsigned)x1 < (unsigned)S);
    bool vy0 = ((unsigned)y0 < (unsigned)S);
    bool vy1 = ((unsigned)y1 < (unsigned)S);

    float w00 = (vx0 && vy0) ? (1.0f - wy) * (1.0f - wx) : 0.0f;
    float w01 = (vx1 && vy0) ? (1.0f - wy) * wx          : 0.0f;
    float w10 = (vx0 && vy1) ? wy * (1.0f - wx)          : 0.0f;
    float w11 = (vx1 && vy1) ? wy * wx                   : 0.0f;

    int xc0 = min(max(x0, 0), S - 1), xc1 = min(max(x1, 0), S - 1);
    int yc0 = min(max(y0, 0), S - 1), yc1 = min(max(y1, 0), S - 1);

    int o00 = yc0 * S + xc0, o01 = yc0 * S + xc1;
    int o10 = yc1 * S + xc0, o11 = yc1 * S + xc1;

    const float* pb = tp + (size_t)p * C * (S * S);
    float r[4];
    #pragma unroll
    for (int j = 0; j < 4; ++j) {
        const float* ch = pb + (size_t)(4 * t + j) * (S * S);
        r[j] = w00 * ch[o00] + w01 * ch[o01] + w10 * ch[o10] + w11 * ch[o11];
    }
    float4 v = make_float4(r[0], r[1], r[2], r[3]);
    *reinterpret_cast<float4*>(out + (size_t)gi * 64 + 4 * t) = v;
}

} // namespace

extern "C" void kernel_launch(void* const* d_in, const int* in_sizes, int n_in,
                              void* d_out, int out_size, void* d_ws, size_t ws_size,
                              hipStream_t stream)
{
    const float* coords  = (const float*)d_in[0];  // (N, M, 3) f32
    const float* tplanes = (const float*)d_in[1];  // (1, 3, C, S, S) f32
    float* out = (float*)d_out;                    // (N, M, 3*C) f32

    int total_sp = in_sizes[0];                    // N*M*3
    int total_s  = total_sp / 3;                   // N*M samples

    // ws layout: bincnt[3072] | ovf_cnt | pad | ovf[8192] u64 | slots[3072*CAP] u64
    const size_t bincntOff = 0;
    const size_t ovfcntOff = (size_t)NBINS * 4;            // 12288
    const size_t ovfOff    = 12352;
    const size_t slotsOff  = ovfOff + (size_t)OVF_CAP * 8; // 77888 (8B aligned)
    const size_t need      = slotsOff + (size_t)NBINS * CAP * 8;  // ~18.4 MB

    if (ws_size >= need) {
        int* bincnt  = (int*)((char*)d_ws + bincntOff);
        int* ovf_cnt = (int*)((char*)d_ws + ovfcntOff);
        u64* ovf     = (u64*)((char*)d_ws + ovfOff);
        u64* slots   = (u64*)((char*)d_ws + slotsOff);

        int nb_bin = (total_s + 512 * BIN_IT - 1) / (512 * BIN_IT);

        hipMemsetAsync(d_ws, 0, ovfcntOff + 64, stream);   // bincnt + ovf_cnt
        tp_bin<<<nb_bin, 512, 0, stream>>>(coords, total_s, bincnt, slots, ovf, ovf_cnt);
        tp_sample_tiled<<<NBINS, 512, 0, stream>>>(tplanes, bincnt, slots,
                                                   ovf, ovf_cnt, out);
    } else {
        int nb_sm = (total_sp * 16 + 255) / 256;
        tp_sample_direct<<<nb_sm, 256, 0, stream>>>(coords, tplanes, out, total_sp);
    }
}